// Round 1
// baseline (1217.052 us; speedup 1.0000x reference)
//
#include <hip/hip_runtime.h>
#include <hip/hip_bf16.h>

// Problem constants (hard-coded; G=8, H=4096, I=1536, M=16384, m_splits=2048)
#define G_  8
#define H_  4096
#define I_  1536
#define MS_ 2048
#define BM  128
#define BN  128
#define BK  32

typedef float  f32x4  __attribute__((ext_vector_type(4)));
typedef __bf16 bf16x8 __attribute__((ext_vector_type(8)));
typedef unsigned int   u32;
typedef unsigned short u16;

// Async global->LDS, 16B per lane. LDS dest = wave-uniform base + lane*16.
__device__ __forceinline__ void async16(const void* g, void* l) {
    __builtin_amdgcn_global_load_lds(
        (__attribute__((address_space(1))) u32*)g,
        (__attribute__((address_space(3))) u32*)l, 16, 0, 0);
}

// RNE f32 -> bf16 pack of two floats into one u32 (lo = a, hi = b).
__device__ __forceinline__ u32 pack2_bf16(float a, float b) {
    u32 ua = __float_as_uint(a), ub = __float_as_uint(b);
    ua += 0x7fffu + ((ua >> 16) & 1u);
    ub += 0x7fffu + ((ub >> 16) & 1u);
    return (ua >> 16) | (ub & 0xffff0000u);
}

// Pass 1: fp32 -> bf16 bulk convert (8 elems/thread/iter, 16B stores).
__global__ void cvt_bf16(const float* __restrict__ in, u32* __restrict__ out, int n8) {
    int i = blockIdx.x * blockDim.x + threadIdx.x;
    int stride = gridDim.x * blockDim.x;
    for (; i < n8; i += stride) {
        const float4* p = (const float4*)in + (size_t)i * 2;
        float4 a = p[0], b = p[1];
        uint4 r;
        r.x = pack2_bf16(a.x, a.y);
        r.y = pack2_bf16(a.z, a.w);
        r.z = pack2_bf16(b.x, b.y);
        r.w = pack2_bf16(b.z, b.w);
        ((uint4*)out)[i] = r;
    }
}

// Pass 2: grouped GEMM + fused SwiGLU.
// Block: 256 threads = 4 waves (2x2). Block tile: 128 rows x (128 gate + 128 up cols).
// Each wave: 64x64 gate + 64x64 up via 16x16x32 bf16 MFMA.
// WSPATH=true: stage bf16 from workspace via global_load_lds (m97 structure).
// WSPATH=false: stage fp32 from inputs, convert in-register, ds_write.
template <bool WSPATH>
__global__ __launch_bounds__(256, 2) void gemm_swiglu(
    const float* __restrict__ x, const float* __restrict__ w,
    const u16* __restrict__ xbf, const u16* __restrict__ wbf,
    float* __restrict__ out) {
    __shared__ __align__(16) u16 As[BM * BK];       //  8 KiB, row-major [128][32]
    __shared__ __align__(16) u16 Bs[2 * BN * BK];   // 16 KiB, rows 0-127 gate, 128-255 up

    const int g    = blockIdx.z;
    const int m0   = blockIdx.y * BM;   // row offset within group
    const int n0   = blockIdx.x * BN;   // gate column offset
    const int tid  = threadIdx.x;
    const int lane = tid & 63;
    const int wid  = tid >> 6;
    const int wm   = (wid >> 1) * 64;
    const int wn   = (wid & 1) * 64;

    f32x4 accg[4][4], accu[4][4];
#pragma unroll
    for (int i = 0; i < 4; ++i)
#pragma unroll
        for (int j = 0; j < 4; ++j) {
            accg[i][j] = f32x4{0.f, 0.f, 0.f, 0.f};
            accu[i][j] = f32x4{0.f, 0.f, 0.f, 0.f};
        }

    const u16*   xbf_b = xbf + (size_t)(g * MS_ + m0) * H_;
    const u16*   wbf_b = wbf + (size_t)g * (2 * I_) * H_;
    const float* x_b   = x   + (size_t)(g * MS_ + m0) * H_;
    const float* w_b   = w   + (size_t)g * (2 * I_) * H_;

    const int lr4 = lane >> 2;        // 0..15: row within 16-row LDS chunk
    const int lc4 = (lane & 3) * 8;   // k-offset in elems (0,8,16,24)
    const int fr  = lane & 15;        // fragment row/col
    const int kq  = (lane >> 4) * 8;  // fragment k-offset

    for (int k0 = 0; k0 < H_; k0 += BK) {
        if constexpr (WSPATH) {
            // A tile: 8 KiB = 8 chunks of 1 KiB; 2 per wave.
#pragma unroll
            for (int j = 0; j < 2; ++j) {
                int chunk = wid * 2 + j;            // 0..7 (wave-uniform)
                int row   = chunk * 16 + lr4;       // 0..127
                async16(xbf_b + (size_t)row * H_ + (k0 + lc4),
                        (char*)As + chunk * 1024);
            }
            // B tile (gate+up): 16 KiB = 16 chunks; 4 per wave.
#pragma unroll
            for (int j = 0; j < 4; ++j) {
                int chunk = wid * 4 + j;            // 0..15 (wave-uniform)
                int row   = chunk * 16 + lr4;       // 0..255
                int wrow  = row < BN ? (n0 + row) : (I_ + n0 + row - BN);
                async16(wbf_b + (size_t)wrow * H_ + (k0 + lc4),
                        (char*)Bs + chunk * 1024);
            }
            asm volatile("s_waitcnt vmcnt(0)" ::: "memory");
        } else {
            const int r  = tid >> 3;
            const int c4 = (tid & 7) * 4;
#pragma unroll
            for (int p = 0; p < 4; ++p) {
                int row  = r + p * 32;
                float4 v = *(const float4*)(x_b + (size_t)row * H_ + k0 + c4);
                uint2 pk;
                pk.x = pack2_bf16(v.x, v.y);
                pk.y = pack2_bf16(v.z, v.w);
                *(uint2*)&As[row * BK + c4] = pk;
            }
#pragma unroll
            for (int p = 0; p < 8; ++p) {
                int row  = r + p * 32;
                int wrow = row < BN ? (n0 + row) : (I_ + n0 + row - BN);
                float4 v = *(const float4*)(w_b + (size_t)wrow * H_ + k0 + c4);
                uint2 pk;
                pk.x = pack2_bf16(v.x, v.y);
                pk.y = pack2_bf16(v.z, v.w);
                *(uint2*)&Bs[row * BK + c4] = pk;
            }
        }
        __syncthreads();

        bf16x8 af[4], bg[4], bu[4];
#pragma unroll
        for (int t = 0; t < 4; ++t)
            af[t] = *(const bf16x8*)&As[(wm + t * 16 + fr) * BK + kq];
#pragma unroll
        for (int t = 0; t < 4; ++t) {
            bg[t] = *(const bf16x8*)&Bs[(wn + t * 16 + fr) * BK + kq];
            bu[t] = *(const bf16x8*)&Bs[(BN + wn + t * 16 + fr) * BK + kq];
        }
#pragma unroll
        for (int mt = 0; mt < 4; ++mt)
#pragma unroll
            for (int nt = 0; nt < 4; ++nt) {
                accg[mt][nt] = __builtin_amdgcn_mfma_f32_16x16x32_bf16(
                    af[mt], bg[nt], accg[mt][nt], 0, 0, 0);
                accu[mt][nt] = __builtin_amdgcn_mfma_f32_16x16x32_bf16(
                    af[mt], bu[nt], accu[mt][nt], 0, 0, 0);
            }
        __syncthreads();
    }

    // Epilogue: C/D layout col = lane&15, row = (lane>>4)*4 + i  [m89-verified]
    const int orow_b = g * MS_ + m0 + wm + (lane >> 4) * 4;
    const int ocol_b = n0 + wn + fr;
#pragma unroll
    for (int mt = 0; mt < 4; ++mt)
#pragma unroll
        for (int nt = 0; nt < 4; ++nt)
#pragma unroll
            for (int i = 0; i < 4; ++i) {
                float gv = accg[mt][nt][i];
                float uv = accu[mt][nt][i];
                float s  = gv / (1.0f + __expf(-gv));  // silu(gate)
                out[(size_t)(orow_b + mt * 16 + i) * I_ + (ocol_b + nt * 16)] = s * uv;
            }
}

extern "C" void kernel_launch(void* const* d_in, const int* in_sizes, int n_in,
                              void* d_out, int out_size, void* d_ws, size_t ws_size,
                              hipStream_t stream) {
    const float* x = (const float*)d_in[0];
    const float* w = (const float*)d_in[1];
    float* out = (float*)d_out;

    const size_t xe = (size_t)G_ * MS_ * H_;        //  67,108,864 elems
    const size_t we = (size_t)G_ * 2 * I_ * H_;     // 100,663,296 elems
    const size_t need = (xe + we) * sizeof(u16);    // 320 MiB

    dim3 grid(I_ / BN, MS_ / BM, G_);               // (12, 16, 8)

    if (ws_size >= need) {
        u16* xbf = (u16*)d_ws;
        u16* wbf = xbf + xe;
        cvt_bf16<<<4096, 256, 0, stream>>>(x, (u32*)xbf, (int)(xe / 8));
        cvt_bf16<<<4096, 256, 0, stream>>>(w, (u32*)wbf, (int)(we / 8));
        gemm_swiglu<true><<<grid, 256, 0, stream>>>(x, w, xbf, wbf, out);
    } else {
        gemm_swiglu<false><<<grid, 256, 0, stream>>>(x, w, nullptr, nullptr, out);
    }
}